// Round 8
// baseline (450.524 us; speedup 1.0000x reference)
//
#include <hip/hip_runtime.h>

#define DM 1024
#define NH 16
#define HD 64
#define BB 2
#define SS 2048
#define MTOT (BB*SS)   // 4096 rows of x
#define NTOT (4*DM)    // 4096 projection outputs

typedef __attribute__((ext_vector_type(8))) short short8;  // 8 bf16 (4 VGPRs)
typedef __attribute__((ext_vector_type(4))) float f32x4;   // 4 f32

#define MFMA(a,b,c) __builtin_amdgcn_mfma_f32_16x16x32_bf16((a),(b),(c),0,0,0)

__device__ inline unsigned short f2bf(float f) {
  union { float f; unsigned u; } v; v.f = f;
  unsigned r = v.u + 0x7FFFu + ((v.u >> 16) & 1u);  // RNE
  return (unsigned short)(r >> 16);
}

__device__ inline void gload_lds16(const void* g, void* l) {
  void* gnc = const_cast<void*>(g);
  __builtin_amdgcn_global_load_lds(
      (__attribute__((address_space(1))) void*)gnc,
      (__attribute__((address_space(3))) void*)l, 16, 0, 0);
}

// ---------------- K0: f32 -> bf16 conversion (x and 4 weight mats) ----------
__global__ __launch_bounds__(256) void k_convert(
    const float* __restrict__ x, const float* __restrict__ w0,
    const float* __restrict__ w1, const float* __restrict__ w2,
    const float* __restrict__ w3,
    unsigned short* __restrict__ xb, unsigned short* __restrict__ wb) {
  const int T4 = (MTOT * DM) / 4;  // 1M float4 per buffer
  int stride = gridDim.x * blockDim.x;
  for (int i = blockIdx.x * blockDim.x + threadIdx.x; i < 2 * T4; i += stride) {
    const float* src; unsigned short* dst;
    if (i < T4) { src = x + (size_t)i * 4; dst = xb + (size_t)i * 4; }
    else {
      int flat = (i - T4) * 4;
      int sel = flat >> 20;
      int off = flat & ((1 << 20) - 1);
      const float* w = (sel == 0) ? w0 : (sel == 1) ? w1 : (sel == 2) ? w2 : w3;
      src = w + off; dst = wb + flat;
    }
    float4 v = *(const float4*)src;
    ushort4 o; o.x = f2bf(v.x); o.y = f2bf(v.y); o.z = f2bf(v.z); o.w = f2bf(v.w);
    *(ushort4*)dst = o;
  }
}

// ---------------- K1: fused projection GEMM [4096,1024]x[4096,1024]^T -------
__global__ __launch_bounds__(256) void k_proj(
    const unsigned short* __restrict__ xb, const unsigned short* __restrict__ wb,
    const float* __restrict__ bbd, const float* __restrict__ bq,
    const float* __restrict__ bk, const float* __restrict__ bv,
    const float* __restrict__ radial,
    float* __restrict__ outbd,
    unsigned short* __restrict__ qb, unsigned short* __restrict__ kb,
    unsigned short* __restrict__ vb) {
  __shared__ unsigned short lsA[128 * 64];
  __shared__ unsigned short lsB[128 * 64];
  const int tid = threadIdx.x;
  const int wave = tid >> 6, lane = tid & 63;
  const int wr = wave >> 1, wc = wave & 1;   // 2x2 wave grid, 64x64 per wave
  // bijective XCD swizzle: 1024 blocks % 8 == 0
  const int lin = blockIdx.y * gridDim.x + blockIdx.x;
  const int swz = (lin & 7) * 128 + (lin >> 3);
  const int m0 = (swz >> 5) * 128, n0 = (swz & 31) * 128;
  const int ro = lane & 15, gg = lane >> 4;
  const int srow = lane >> 3;        // 0..7 within an 8-row chunk
  const int scol = (lane & 7) * 8;   // bf16 col within 64
  f32x4 acc[4][4] = {};
  for (int kt = 0; kt < DM / 64; ++kt) {
    __syncthreads();
    #pragma unroll
    for (int i = 0; i < 4; ++i) {
      int c = wave * 4 + i;          // chunk 0..15, 8 rows each
      const unsigned short* ga = xb + (size_t)(m0 + c * 8 + srow) * DM + kt * 64 + scol;
      gload_lds16(ga, (void*)(lsA + c * 512));
      const unsigned short* gb = wb + (size_t)(n0 + c * 8 + srow) * DM + kt * 64 + scol;
      gload_lds16(gb, (void*)(lsB + c * 512));
    }
    __syncthreads();
    #pragma unroll
    for (int ks = 0; ks < 2; ++ks) {
      short8 a[4], b[4];
      int ko = ks * 32 + gg * 8;
      #pragma unroll
      for (int r = 0; r < 4; ++r)
        a[r] = *(const short8*)&lsA[(wr * 64 + r * 16 + ro) * 64 + ko];
      #pragma unroll
      for (int c = 0; c < 4; ++c)
        b[c] = *(const short8*)&lsB[(wc * 64 + c * 16 + ro) * 64 + ko];
      #pragma unroll
      for (int r = 0; r < 4; ++r)
        #pragma unroll
        for (int c = 0; c < 4; ++c)
          acc[r][c] = MFMA(a[r], b[c], acc[r][c]);
    }
  }
  const int which = n0 >> 10;  // uniform per block
  #pragma unroll
  for (int r = 0; r < 4; ++r) {
    const int mbase = m0 + wr * 64 + r * 16 + gg * 4;
    #pragma unroll
    for (int c = 0; c < 4; ++c) {
      const int n = n0 + wc * 64 + c * 16 + ro;
      const int nn = n & 1023;
      #pragma unroll
      for (int j = 0; j < 4; ++j) {
        const int m = mbase + j;
        float v = acc[r][c][j];
        if (which == 0) {
          outbd[(size_t)m * DM + nn] = v + bbd[nn];
        } else {
          const int h = nn >> 6, d = nn & 63;
          const int b2 = m >> 11, s = m & 2047;
          const size_t o = (((size_t)(b2 * NH + h)) * SS + s) * HD + d;
          if (which == 1) {
            float sg = 1.f / (1.f + __expf(-radial[h]));
            qb[o] = f2bf((v + bq[nn]) * sg);
          } else if (which == 2) {
            kb[o] = f2bf(v + bk[nn]);
          } else {
            vb[o] = f2bf(v + bv[nn]);
          }
        }
      }
    }
  }
}

// ---------------- K1b: transpose V -> vt[bh][64][2048] ----------------------
__global__ __launch_bounds__(256) void k_vt(
    const unsigned short* __restrict__ vb, unsigned short* __restrict__ vt) {
  __shared__ unsigned short t[64][65];
  const int bh = blockIdx.y, st = blockIdx.x;
  const int tid = threadIdx.x;
  const int r = tid >> 2, c4 = (tid & 3) * 16;
  const unsigned short* src = vb + ((size_t)bh * SS + st * 64 + r) * HD + c4;
  #pragma unroll
  for (int i = 0; i < 16; i += 4) {
    ushort4 v = *(const ushort4*)(src + i);
    t[r][c4 + i + 0] = v.x; t[r][c4 + i + 1] = v.y;
    t[r][c4 + i + 2] = v.z; t[r][c4 + i + 3] = v.w;
  }
  __syncthreads();
  const int dd = tid >> 2, s4 = (tid & 3) * 16;
  unsigned short* dst = vt + ((size_t)bh * HD + dd) * SS + st * 64 + s4;
  #pragma unroll
  for (int i = 0; i < 16; i += 4) {
    ushort4 o;
    o.x = t[s4 + i + 0][dd]; o.y = t[s4 + i + 1][dd];
    o.z = t[s4 + i + 2][dd]; o.w = t[s4 + i + 3][dd];
    *(ushort4*)(dst + i) = o;
  }
}

// ---------------- K2: fused scores + tropical softmax + attn write + PV -----
// Fully wave-independent: each wave owns 16 q-rows, streams K / V^T straight
// from global to registers in batches (L2-resident: XCD swizzle gives each
// XCD 4 heads = 2 MB < 4 MB L2). NO barriers, no shared staging. P
// redistribution uses a wave-PRIVATE 2 KB LDS tile (lgkmcnt only).
// Nontemporal attn stores bypass L2, keeping K/V resident.
__global__ __launch_bounds__(256) void k_attn_pv(
    const unsigned short* __restrict__ qb, const unsigned short* __restrict__ kb,
    const unsigned short* __restrict__ vt, const float* __restrict__ tsc,
    float* __restrict__ attn, float* __restrict__ out) {
  __shared__ __align__(16) unsigned short pt[4][16 * 64];    // 8 KB total
  // bijective XCD swizzle: p -> (p&7)*128 + p>>3; XCD j owns bh 4j..4j+3
  const int p = blockIdx.y * gridDim.x + blockIdx.x;
  const int t = (p & 7) * 128 + (p >> 3);
  const int bh = t >> 5, qt = t & 31;
  const int tid = threadIdx.x, wave = tid >> 6, lane = tid & 63;
  const int ro = lane & 15, gg = lane >> 4;

  // Q straight to registers (row = qt*64 + wave*16 + ro)
  const unsigned short* qrow =
      qb + ((size_t)bh * SS + qt * 64 + wave * 16 + ro) * HD;
  short8 aq0 = *(const short8*)(qrow + gg * 8);
  short8 aq1 = *(const short8*)(qrow + 32 + gg * 8);
  const float fac = tsc[0] * 0.125f;  // tropical_scale / sqrt(64)

  // per-lane K fragment base: row ro of each 16-row k-tile, cols gg*8 (+32)
  const unsigned short* kbase = kb + (size_t)bh * SS * HD + ro * HD + gg * 8;
  const unsigned short* vbase = vt + (size_t)bh * HD * SS + ro * SS + gg * 8;

  // ---- pass 1: row sums of exp(s*fac), batch-4 k-tiles ----
  float psum = 0.f;
  for (int kt4 = 0; kt4 < 32; ++kt4) {
    short8 b0[4], b1[4];
    #pragma unroll
    for (int i = 0; i < 4; ++i) {
      const unsigned short* kp = kbase + (size_t)(kt4 * 4 + i) * 16 * HD;
      b0[i] = *(const short8*)kp;
      b1[i] = *(const short8*)(kp + 32);
    }
    #pragma unroll
    for (int i = 0; i < 4; ++i) {
      f32x4 sf = {};
      sf = MFMA(b0[i], aq0, sf);   // lane: q=ro, k = (kt4*4+i)*16 + gg*4 + reg
      sf = MFMA(b1[i], aq1, sf);
      psum += __expf(sf[0] * fac) + __expf(sf[1] * fac)
            + __expf(sf[2] * fac) + __expf(sf[3] * fac);
    }
  }
  psum += __shfl_xor(psum, 16);
  psum += __shfl_xor(psum, 32);
  const float rsum = 1.f / (psum + 1e-8f);

  // ---- pass 2: recompute, write normalized attn (nt), PV ----
  float* ab = attn + ((size_t)bh * SS + qt * 64 + wave * 16 + ro) * SS;
  unsigned short* pw = &pt[wave][0];
  f32x4 acc[4] = {};
  for (int ct = 0; ct < 32; ++ct) {   // 64-k chunks
    short8 kb0[4], kb1[4], vv0[4], vv1[4];
    #pragma unroll
    for (int i = 0; i < 4; ++i) {
      const unsigned short* kp = kbase + (size_t)(ct * 4 + i) * 16 * HD;
      kb0[i] = *(const short8*)kp;
      kb1[i] = *(const short8*)(kp + 32);
    }
    #pragma unroll
    for (int dc = 0; dc < 4; ++dc) {
      const unsigned short* vp = vbase + (size_t)dc * 16 * SS + ct * 64;
      vv0[dc] = *(const short8*)vp;
      vv1[dc] = *(const short8*)(vp + 32);
    }
    #pragma unroll
    for (int sub = 0; sub < 4; ++sub) {
      f32x4 sf = {};
      sf = MFMA(kb0[sub], aq0, sf);
      sf = MFMA(kb1[sub], aq1, sf);
      f32x4 st;
      st[0] = __expf(sf[0] * fac) * rsum; st[1] = __expf(sf[1] * fac) * rsum;
      st[2] = __expf(sf[2] * fac) * rsum; st[3] = __expf(sf[3] * fac) * rsum;
      __builtin_nontemporal_store(st, (f32x4*)(ab + (ct * 4 + sub) * 16 + gg * 4));
      unsigned w0, w1;
      asm("v_cvt_pk_bf16_f32 %0, %1, %2" : "=v"(w0) : "v"(st[0]), "v"(st[1]));
      asm("v_cvt_pk_bf16_f32 %0, %1, %2" : "=v"(w1) : "v"(st[2]), "v"(st[3]));
      // P row ro, k-slot = sub*2 + (gg>>1), swizzled by ro&7; 8B half = gg&1
      const int slot = (sub * 2 + (gg >> 1)) ^ (ro & 7);
      *(uint2*)((char*)pw + ro * 128 + slot * 16 + (gg & 1) * 8) = make_uint2(w0, w1);
    }
    // PV: 2 k-steps of 32 over this 64-k chunk (wave-private LDS, no barrier)
    {
      const int pslot0 = (0 * 4 + gg) ^ (ro & 7);
      short8 pa0 = *(const short8*)((const char*)pw + ro * 128 + pslot0 * 16);
      #pragma unroll
      for (int dc = 0; dc < 4; ++dc)
        acc[dc] = MFMA(pa0, vv0[dc], acc[dc]);
      const int pslot1 = (1 * 4 + gg) ^ (ro & 7);
      short8 pa1 = *(const short8*)((const char*)pw + ro * 128 + pslot1 * 16);
      #pragma unroll
      for (int dc = 0; dc < 4; ++dc)
        acc[dc] = MFMA(pa1, vv1[dc], acc[dc]);
    }
  }

  // epilogue: out += PV (boundary already written by k_proj)
  const int b2 = bh >> 4, h = bh & 15;
  const int s0 = qt * 64 + wave * 16 + gg * 4;
  #pragma unroll
  for (int dc = 0; dc < 4; ++dc)
    #pragma unroll
    for (int j = 0; j < 4; ++j) {
      size_t o = ((size_t)b2 * SS + s0 + j) * DM + h * HD + dc * 16 + ro;
      out[o] += acc[dc][j];
    }
}

extern "C" void kernel_launch(void* const* d_in, const int* in_sizes, int n_in,
                              void* d_out, int out_size, void* d_ws, size_t ws_size,
                              hipStream_t stream) {
  (void)in_sizes; (void)n_in; (void)out_size; (void)ws_size;
  const float* x   = (const float*)d_in[0];
  const float* Wb  = (const float*)d_in[1];
  const float* bb  = (const float*)d_in[2];
  const float* Wq  = (const float*)d_in[3];
  const float* bq  = (const float*)d_in[4];
  const float* Wk  = (const float*)d_in[5];
  const float* bk  = (const float*)d_in[6];
  const float* Wv  = (const float*)d_in[7];
  const float* bv  = (const float*)d_in[8];
  const float* rad = (const float*)d_in[9];
  const float* tsc = (const float*)d_in[10];

  float* out  = (float*)d_out;
  float* attn = out + (size_t)MTOT * DM;  // second output, also early scratch

  // ws: qb(8MB) kb(8MB) vt(8MB)
  unsigned short* qb = (unsigned short*)d_ws;
  unsigned short* kb = qb + (size_t)4 * 1024 * 1024;
  unsigned short* vt = kb + (size_t)4 * 1024 * 1024;

  // scratch carved from the attn output region (overwritten later by k_attn_pv)
  unsigned short* xb = (unsigned short*)attn;
  unsigned short* wb = xb + (size_t)4 * 1024 * 1024;
  unsigned short* vb = wb + (size_t)4 * 1024 * 1024;

  k_convert<<<2048, 256, 0, stream>>>(x, Wb, Wq, Wk, Wv, xb, wb);
  k_proj<<<dim3(32, 32), 256, 0, stream>>>(xb, wb, bb, bq, bk, bv, rad, out, qb, kb, vb);
  k_vt<<<dim3(32, 32), 256, 0, stream>>>(vb, vt);
  k_attn_pv<<<dim3(32, 32), 256, 0, stream>>>(qb, kb, vt, tsc, attn, out);
}

// Round 9
// 288.554 us; speedup vs baseline: 1.5613x; 1.5613x over previous
//
#include <hip/hip_runtime.h>

#define DM 1024
#define NH 16
#define HD 64
#define BB 2
#define SS 2048
#define MTOT (BB*SS)   // 4096 rows of x
#define NTOT (4*DM)    // 4096 projection outputs

typedef __attribute__((ext_vector_type(8))) short short8;  // 8 bf16 (4 VGPRs)
typedef __attribute__((ext_vector_type(4))) float f32x4;   // 4 f32

#define MFMA(a,b,c) __builtin_amdgcn_mfma_f32_16x16x32_bf16((a),(b),(c),0,0,0)

__device__ inline unsigned short f2bf(float f) {
  union { float f; unsigned u; } v; v.f = f;
  unsigned r = v.u + 0x7FFFu + ((v.u >> 16) & 1u);  // RNE
  return (unsigned short)(r >> 16);
}

__device__ inline void gload_lds16(const void* g, void* l) {
  void* gnc = const_cast<void*>(g);
  __builtin_amdgcn_global_load_lds(
      (__attribute__((address_space(1))) void*)gnc,
      (__attribute__((address_space(3))) void*)l, 16, 0, 0);
}

// ---------------- K0: f32 -> bf16 conversion (x and 4 weight mats) ----------
__global__ __launch_bounds__(256) void k_convert(
    const float* __restrict__ x, const float* __restrict__ w0,
    const float* __restrict__ w1, const float* __restrict__ w2,
    const float* __restrict__ w3,
    unsigned short* __restrict__ xb, unsigned short* __restrict__ wb) {
  const int T4 = (MTOT * DM) / 4;  // 1M float4 per buffer
  int stride = gridDim.x * blockDim.x;
  for (int i = blockIdx.x * blockDim.x + threadIdx.x; i < 2 * T4; i += stride) {
    const float* src; unsigned short* dst;
    if (i < T4) { src = x + (size_t)i * 4; dst = xb + (size_t)i * 4; }
    else {
      int flat = (i - T4) * 4;
      int sel = flat >> 20;
      int off = flat & ((1 << 20) - 1);
      const float* w = (sel == 0) ? w0 : (sel == 1) ? w1 : (sel == 2) ? w2 : w3;
      src = w + off; dst = wb + flat;
    }
    float4 v = *(const float4*)src;
    ushort4 o; o.x = f2bf(v.x); o.y = f2bf(v.y); o.z = f2bf(v.z); o.w = f2bf(v.w);
    *(ushort4*)dst = o;
  }
}

// ---------------- K1: fused projection GEMM [4096,1024]x[4096,1024]^T -------
__global__ __launch_bounds__(256) void k_proj(
    const unsigned short* __restrict__ xb, const unsigned short* __restrict__ wb,
    const float* __restrict__ bbd, const float* __restrict__ bq,
    const float* __restrict__ bk, const float* __restrict__ bv,
    const float* __restrict__ radial,
    float* __restrict__ outbd,
    unsigned short* __restrict__ qb, unsigned short* __restrict__ kb,
    unsigned short* __restrict__ vb) {
  __shared__ unsigned short lsA[128 * 64];
  __shared__ unsigned short lsB[128 * 64];
  const int tid = threadIdx.x;
  const int wave = tid >> 6, lane = tid & 63;
  const int wr = wave >> 1, wc = wave & 1;   // 2x2 wave grid, 64x64 per wave
  // bijective XCD swizzle: 1024 blocks % 8 == 0
  const int lin = blockIdx.y * gridDim.x + blockIdx.x;
  const int swz = (lin & 7) * 128 + (lin >> 3);
  const int m0 = (swz >> 5) * 128, n0 = (swz & 31) * 128;
  const int ro = lane & 15, gg = lane >> 4;
  const int srow = lane >> 3;        // 0..7 within an 8-row chunk
  const int scol = (lane & 7) * 8;   // bf16 col within 64
  f32x4 acc[4][4] = {};
  for (int kt = 0; kt < DM / 64; ++kt) {
    __syncthreads();
    #pragma unroll
    for (int i = 0; i < 4; ++i) {
      int c = wave * 4 + i;          // chunk 0..15, 8 rows each
      const unsigned short* ga = xb + (size_t)(m0 + c * 8 + srow) * DM + kt * 64 + scol;
      gload_lds16(ga, (void*)(lsA + c * 512));
      const unsigned short* gb = wb + (size_t)(n0 + c * 8 + srow) * DM + kt * 64 + scol;
      gload_lds16(gb, (void*)(lsB + c * 512));
    }
    __syncthreads();
    #pragma unroll
    for (int ks = 0; ks < 2; ++ks) {
      short8 a[4], b[4];
      int ko = ks * 32 + gg * 8;
      #pragma unroll
      for (int r = 0; r < 4; ++r)
        a[r] = *(const short8*)&lsA[(wr * 64 + r * 16 + ro) * 64 + ko];
      #pragma unroll
      for (int c = 0; c < 4; ++c)
        b[c] = *(const short8*)&lsB[(wc * 64 + c * 16 + ro) * 64 + ko];
      #pragma unroll
      for (int r = 0; r < 4; ++r)
        #pragma unroll
        for (int c = 0; c < 4; ++c)
          acc[r][c] = MFMA(a[r], b[c], acc[r][c]);
    }
  }
  const int which = n0 >> 10;  // uniform per block
  #pragma unroll
  for (int r = 0; r < 4; ++r) {
    const int mbase = m0 + wr * 64 + r * 16 + gg * 4;
    #pragma unroll
    for (int c = 0; c < 4; ++c) {
      const int n = n0 + wc * 64 + c * 16 + ro;
      const int nn = n & 1023;
      #pragma unroll
      for (int j = 0; j < 4; ++j) {
        const int m = mbase + j;
        float v = acc[r][c][j];
        if (which == 0) {
          outbd[(size_t)m * DM + nn] = v + bbd[nn];
        } else {
          const int h = nn >> 6, d = nn & 63;
          const int b2 = m >> 11, s = m & 2047;
          const size_t o = (((size_t)(b2 * NH + h)) * SS + s) * HD + d;
          if (which == 1) {
            float sg = 1.f / (1.f + __expf(-radial[h]));
            qb[o] = f2bf((v + bq[nn]) * sg);
          } else if (which == 2) {
            kb[o] = f2bf(v + bk[nn]);
          } else {
            vb[o] = f2bf(v + bv[nn]);
          }
        }
      }
    }
  }
}

// ---------------- K1b: transpose V -> vt[bh][64][2048] ----------------------
__global__ __launch_bounds__(256) void k_vt(
    const unsigned short* __restrict__ vb, unsigned short* __restrict__ vt) {
  __shared__ unsigned short t[64][65];
  const int bh = blockIdx.y, st = blockIdx.x;
  const int tid = threadIdx.x;
  const int r = tid >> 2, c4 = (tid & 3) * 16;
  const unsigned short* src = vb + ((size_t)bh * SS + st * 64 + r) * HD + c4;
  #pragma unroll
  for (int i = 0; i < 16; i += 4) {
    ushort4 v = *(const ushort4*)(src + i);
    t[r][c4 + i + 0] = v.x; t[r][c4 + i + 1] = v.y;
    t[r][c4 + i + 2] = v.z; t[r][c4 + i + 3] = v.w;
  }
  __syncthreads();
  const int dd = tid >> 2, s4 = (tid & 3) * 16;
  unsigned short* dst = vt + ((size_t)bh * HD + dd) * SS + st * 64 + s4;
  #pragma unroll
  for (int i = 0; i < 16; i += 4) {
    ushort4 o;
    o.x = t[s4 + i + 0][dd]; o.y = t[s4 + i + 1][dd];
    o.z = t[s4 + i + 2][dd]; o.w = t[s4 + i + 3][dd];
    *(ushort4*)(dst + i) = o;
  }
}

// ---------------- K2: fused scores + tropical softmax + attn write + PV -----
// Block: 64 q-rows of one (b,h), 4 waves. Q in registers.
// LDS: 4 rotating 8KB buffers (shared between the two passes) + per-wave P.
// Pass 1: 3-deep K prefetch, counted vmcnt(4) + s_barrier, stage AFTER the
//   barrier (no full drains); peeled tail vmcnt(2)/vmcnt(0).
// Pass 2: r6-proven 1-deep K+V with vmcnt(4) (never drains attn stores).
// XCD swizzle: each XCD owns 4 heads (K/V working set 2MB < 4MB L2).
__global__ __launch_bounds__(256) void k_attn_pv(
    const unsigned short* __restrict__ qb, const unsigned short* __restrict__ kb,
    const unsigned short* __restrict__ vt, const float* __restrict__ tsc,
    float* __restrict__ attn, float* __restrict__ out) {
  __shared__ unsigned short lds[4][64 * 64];                 // 32 KB
  __shared__ __align__(16) unsigned short pt[4][16 * 64];    // 8 KB
  // bijective XCD swizzle: p -> (p&7)*128 + p>>3; XCD j owns bh 4j..4j+3
  const int p = blockIdx.y * gridDim.x + blockIdx.x;
  const int t = (p & 7) * 128 + (p >> 3);
  const int bh = t >> 5, qt = t & 31;
  const int tid = threadIdx.x, wave = tid >> 6, lane = tid & 63;
  const int ro = lane & 15, gg = lane >> 4;

  const unsigned short* kb_bh = kb + (size_t)bh * SS * HD;
  const unsigned short* vt_bh = vt + (size_t)bh * HD * SS;

  // staging geometry: thread stages 16B slots (wave*2+i)*64+lane, i=0,1
  int sr0, sc0, sr1, sc1;
  {
    int s0 = (wave * 2 + 0) * 64 + lane;
    int s1 = (wave * 2 + 1) * 64 + lane;
    sr0 = s0 >> 3; sc0 = (s0 & 7) ^ (sr0 & 7);
    sr1 = s1 >> 3; sc1 = (s1 & 7) ^ (sr1 & 7);
  }

#define STAGE_K(buf, kt) do { \
    const unsigned short* g = kb_bh + (size_t)(kt) * 64 * HD; \
    gload_lds16(g + sr0 * 64 + sc0 * 8, (void*)(lds[buf] + (wave * 2 + 0) * 512)); \
    gload_lds16(g + sr1 * 64 + sc1 * 8, (void*)(lds[buf] + (wave * 2 + 1) * 512)); \
  } while (0)
#define STAGE_V(buf, kt) do { \
    const unsigned short* g = vt_bh + (size_t)(kt) * 64; \
    gload_lds16(g + (size_t)sr0 * SS + sc0 * 8, (void*)(lds[buf] + (wave * 2 + 0) * 512)); \
    gload_lds16(g + (size_t)sr1 * SS + sc1 * 8, (void*)(lds[buf] + (wave * 2 + 1) * 512)); \
  } while (0)

  // Q register loads first (2 VMEM); then 3-deep K prefetch (6 VMEM).
  const unsigned short* qrow =
      qb + ((size_t)bh * SS + qt * 64 + wave * 16 + ro) * HD;
  short8 aq0 = *(const short8*)(qrow + gg * 8);
  short8 aq1 = *(const short8*)(qrow + 32 + gg * 8);
  const float fac = tsc[0] * 0.125f;  // tropical_scale / sqrt(64)

  STAGE_K(0, 0); STAGE_K(1, 1); STAGE_K(2, 2);

  // ---- pass 1: row sums of exp(s*fac) ----
  float psum = 0.f;
  auto p1body = [&](int ct) {
    const unsigned short* kbuf = lds[ct & 3];
    #pragma unroll
    for (int sub = 0; sub < 4; ++sub) {
      const int rr = sub * 16 + ro;
      const unsigned short* kr = kbuf + rr * 64;
      short8 b0 = *(const short8*)&kr[(gg ^ (rr & 7)) * 8];
      short8 b1 = *(const short8*)&kr[((4 + gg) ^ (rr & 7)) * 8];
      f32x4 sf = {};
      sf = MFMA(b0, aq0, sf);   // lane: q=ro, k = ct*64+sub*16+gg*4+reg
      sf = MFMA(b1, aq1, sf);
      psum += __expf(sf[0] * fac) + __expf(sf[1] * fac)
            + __expf(sf[2] * fac) + __expf(sf[3] * fac);
    }
  };
  for (int ct = 0; ct < 30; ++ct) {
    asm volatile("s_waitcnt vmcnt(4)" ::: "memory");
    __builtin_amdgcn_s_barrier();
    if (ct < 29) STAGE_K((ct + 3) & 3, ct + 3);
    p1body(ct);
  }
  asm volatile("s_waitcnt vmcnt(2)" ::: "memory");
  __builtin_amdgcn_s_barrier();
  p1body(30);
  asm volatile("s_waitcnt vmcnt(0)" ::: "memory");
  __builtin_amdgcn_s_barrier();
  p1body(31);

  // ---- transition: stage pass-2 chunk 0, reduce psum, full drain once ----
  STAGE_K(0, 0);
  STAGE_V(1, 0);
  psum += __shfl_xor(psum, 16);
  psum += __shfl_xor(psum, 32);
  const float rsum = 1.f / (psum + 1e-8f);
  asm volatile("s_waitcnt vmcnt(0)" ::: "memory");
  __builtin_amdgcn_s_barrier();

  // ---- pass 2: recompute, write normalized attn (nt), PV ----
  // per chunk: [vmcnt(4) waits this chunk's 4 staged loads][s_barrier]
  //            [issue next chunk's 4 loads][consume: 4 stores + P + PV]
  float* ab = attn + ((size_t)bh * SS + qt * 64 + wave * 16 + ro) * SS;
  unsigned short* pw = &pt[wave][0];
  f32x4 acc[4] = {};
  for (int ct = 0; ct < 32; ++ct) {
    asm volatile("s_waitcnt vmcnt(4)" ::: "memory");
    __builtin_amdgcn_s_barrier();
    if (ct < 31) {
      STAGE_K(2 * ((ct + 1) & 1), ct + 1);
      STAGE_V(2 * ((ct + 1) & 1) + 1, ct + 1);
    }
    const unsigned short* kbuf = lds[2 * (ct & 1)];
    const unsigned short* vbuf = lds[2 * (ct & 1) + 1];
    #pragma unroll
    for (int sub = 0; sub < 4; ++sub) {
      const int rr = sub * 16 + ro;
      const unsigned short* kr = kbuf + rr * 64;
      short8 b0 = *(const short8*)&kr[(gg ^ (rr & 7)) * 8];
      short8 b1 = *(const short8*)&kr[((4 + gg) ^ (rr & 7)) * 8];
      f32x4 sf = {};
      sf = MFMA(b0, aq0, sf);
      sf = MFMA(b1, aq1, sf);
      f32x4 st;
      st[0] = __expf(sf[0] * fac) * rsum; st[1] = __expf(sf[1] * fac) * rsum;
      st[2] = __expf(sf[2] * fac) * rsum; st[3] = __expf(sf[3] * fac) * rsum;
      __builtin_nontemporal_store(st, (f32x4*)(ab + (ct * 4 + sub) * 16 + gg * 4));
      unsigned w0, w1;
      asm("v_cvt_pk_bf16_f32 %0, %1, %2" : "=v"(w0) : "v"(st[0]), "v"(st[1]));
      asm("v_cvt_pk_bf16_f32 %0, %1, %2" : "=v"(w1) : "v"(st[2]), "v"(st[3]));
      // P row ro, k-slot = sub*2 + (gg>>1), swizzled by ro&7; 8B half = gg&1
      const int slot = (sub * 2 + (gg >> 1)) ^ (ro & 7);
      *(uint2*)((char*)pw + ro * 128 + slot * 16 + (gg & 1) * 8) = make_uint2(w0, w1);
    }
    // PV: 2 k-steps of 32 over this 64-k chunk
    #pragma unroll
    for (int ks = 0; ks < 2; ++ks) {
      const int pslot = (ks * 4 + gg) ^ (ro & 7);
      short8 pa = *(const short8*)((const char*)pw + ro * 128 + pslot * 16);
      #pragma unroll
      for (int dc = 0; dc < 4; ++dc) {
        const int rr = dc * 16 + ro;
        const int cc = (ks * 4 + gg) ^ (rr & 7);
        short8 bvf = *(const short8*)&vbuf[rr * 64 + cc * 8];
        acc[dc] = MFMA(pa, bvf, acc[dc]);
      }
    }
  }

  // epilogue: out += PV (boundary already written by k_proj)
  const int b2 = bh >> 4, h = bh & 15;
  const int s0 = qt * 64 + wave * 16 + gg * 4;
  #pragma unroll
  for (int dc = 0; dc < 4; ++dc)
    #pragma unroll
    for (int j = 0; j < 4; ++j) {
      size_t o = ((size_t)b2 * SS + s0 + j) * DM + h * HD + dc * 16 + ro;
      out[o] += acc[dc][j];
    }
#undef STAGE_K
#undef STAGE_V
}

extern "C" void kernel_launch(void* const* d_in, const int* in_sizes, int n_in,
                              void* d_out, int out_size, void* d_ws, size_t ws_size,
                              hipStream_t stream) {
  (void)in_sizes; (void)n_in; (void)out_size; (void)ws_size;
  const float* x   = (const float*)d_in[0];
  const float* Wb  = (const float*)d_in[1];
  const float* bb  = (const float*)d_in[2];
  const float* Wq  = (const float*)d_in[3];
  const float* bq  = (const float*)d_in[4];
  const float* Wk  = (const float*)d_in[5];
  const float* bk  = (const float*)d_in[6];
  const float* Wv  = (const float*)d_in[7];
  const float* bv  = (const float*)d_in[8];
  const float* rad = (const float*)d_in[9];
  const float* tsc = (const float*)d_in[10];

  float* out  = (float*)d_out;
  float* attn = out + (size_t)MTOT * DM;  // second output, also early scratch

  // ws: qb(8MB) kb(8MB) vt(8MB)
  unsigned short* qb = (unsigned short*)d_ws;
  unsigned short* kb = qb + (size_t)4 * 1024 * 1024;
  unsigned short* vt = kb + (size_t)4 * 1024 * 1024;

  // scratch carved from the attn output region (overwritten later by k_attn_pv)
  unsigned short* xb = (unsigned short*)attn;
  unsigned short* wb = xb + (size_t)4 * 1024 * 1024;
  unsigned short* vb = wb + (size_t)4 * 1024 * 1024;

  k_convert<<<2048, 256, 0, stream>>>(x, Wb, Wq, Wk, Wv, xb, wb);
  k_proj<<<dim3(32, 32), 256, 0, stream>>>(xb, wb, bb, bq, bk, bv, rad, out, qb, kb, vb);
  k_vt<<<dim3(32, 32), 256, 0, stream>>>(vb, vt);
  k_attn_pv<<<dim3(32, 32), 256, 0, stream>>>(qb, kb, vt, tsc, attn, out);
}

// Round 10
// 275.842 us; speedup vs baseline: 1.6333x; 1.0461x over previous
//
#include <hip/hip_runtime.h>

#define DM 1024
#define NH 16
#define HD 64
#define BB 2
#define SS 2048
#define MTOT (BB*SS)   // 4096 rows of x
#define NTOT (4*DM)    // 4096 projection outputs

typedef __attribute__((ext_vector_type(8))) short short8;  // 8 bf16 (4 VGPRs)
typedef __attribute__((ext_vector_type(4))) float f32x4;   // 4 f32

#define MFMA(a,b,c) __builtin_amdgcn_mfma_f32_16x16x32_bf16((a),(b),(c),0,0,0)

__device__ inline unsigned short f2bf(float f) {
  union { float f; unsigned u; } v; v.f = f;
  unsigned r = v.u + 0x7FFFu + ((v.u >> 16) & 1u);  // RNE
  return (unsigned short)(r >> 16);
}

__device__ inline void gload_lds16(const void* g, void* l) {
  void* gnc = const_cast<void*>(g);
  __builtin_amdgcn_global_load_lds(
      (__attribute__((address_space(1))) void*)gnc,
      (__attribute__((address_space(3))) void*)l, 16, 0, 0);
}

// ---------------- K0: f32 -> bf16 conversion (x and 4 weight mats) ----------
__global__ __launch_bounds__(256) void k_convert(
    const float* __restrict__ x, const float* __restrict__ w0,
    const float* __restrict__ w1, const float* __restrict__ w2,
    const float* __restrict__ w3,
    unsigned short* __restrict__ xb, unsigned short* __restrict__ wb) {
  const int T4 = (MTOT * DM) / 4;  // 1M float4 per buffer
  int stride = gridDim.x * blockDim.x;
  for (int i = blockIdx.x * blockDim.x + threadIdx.x; i < 2 * T4; i += stride) {
    const float* src; unsigned short* dst;
    if (i < T4) { src = x + (size_t)i * 4; dst = xb + (size_t)i * 4; }
    else {
      int flat = (i - T4) * 4;
      int sel = flat >> 20;
      int off = flat & ((1 << 20) - 1);
      const float* w = (sel == 0) ? w0 : (sel == 1) ? w1 : (sel == 2) ? w2 : w3;
      src = w + off; dst = wb + flat;
    }
    float4 v = *(const float4*)src;
    ushort4 o; o.x = f2bf(v.x); o.y = f2bf(v.y); o.z = f2bf(v.z); o.w = f2bf(v.w);
    *(ushort4*)dst = o;
  }
}

// ---------------- K1: fused projection GEMM [4096,1024]x[4096,1024]^T -------
__global__ __launch_bounds__(256) void k_proj(
    const unsigned short* __restrict__ xb, const unsigned short* __restrict__ wb,
    const float* __restrict__ bbd, const float* __restrict__ bq,
    const float* __restrict__ bk, const float* __restrict__ bv,
    const float* __restrict__ radial,
    float* __restrict__ outbd,
    unsigned short* __restrict__ qb, unsigned short* __restrict__ kb,
    unsigned short* __restrict__ vb) {
  __shared__ unsigned short lsA[128 * 64];
  __shared__ unsigned short lsB[128 * 64];
  const int tid = threadIdx.x;
  const int wave = tid >> 6, lane = tid & 63;
  const int wr = wave >> 1, wc = wave & 1;   // 2x2 wave grid, 64x64 per wave
  // bijective XCD swizzle: 1024 blocks % 8 == 0
  const int lin = blockIdx.y * gridDim.x + blockIdx.x;
  const int swz = (lin & 7) * 128 + (lin >> 3);
  const int m0 = (swz >> 5) * 128, n0 = (swz & 31) * 128;
  const int ro = lane & 15, gg = lane >> 4;
  const int srow = lane >> 3;        // 0..7 within an 8-row chunk
  const int scol = (lane & 7) * 8;   // bf16 col within 64
  f32x4 acc[4][4] = {};
  for (int kt = 0; kt < DM / 64; ++kt) {
    __syncthreads();
    #pragma unroll
    for (int i = 0; i < 4; ++i) {
      int c = wave * 4 + i;          // chunk 0..15, 8 rows each
      const unsigned short* ga = xb + (size_t)(m0 + c * 8 + srow) * DM + kt * 64 + scol;
      gload_lds16(ga, (void*)(lsA + c * 512));
      const unsigned short* gb = wb + (size_t)(n0 + c * 8 + srow) * DM + kt * 64 + scol;
      gload_lds16(gb, (void*)(lsB + c * 512));
    }
    __syncthreads();
    #pragma unroll
    for (int ks = 0; ks < 2; ++ks) {
      short8 a[4], b[4];
      int ko = ks * 32 + gg * 8;
      #pragma unroll
      for (int r = 0; r < 4; ++r)
        a[r] = *(const short8*)&lsA[(wr * 64 + r * 16 + ro) * 64 + ko];
      #pragma unroll
      for (int c = 0; c < 4; ++c)
        b[c] = *(const short8*)&lsB[(wc * 64 + c * 16 + ro) * 64 + ko];
      #pragma unroll
      for (int r = 0; r < 4; ++r)
        #pragma unroll
        for (int c = 0; c < 4; ++c)
          acc[r][c] = MFMA(a[r], b[c], acc[r][c]);
    }
  }
  const int which = n0 >> 10;  // uniform per block
  #pragma unroll
  for (int r = 0; r < 4; ++r) {
    const int mbase = m0 + wr * 64 + r * 16 + gg * 4;
    #pragma unroll
    for (int c = 0; c < 4; ++c) {
      const int n = n0 + wc * 64 + c * 16 + ro;
      const int nn = n & 1023;
      #pragma unroll
      for (int j = 0; j < 4; ++j) {
        const int m = mbase + j;
        float v = acc[r][c][j];
        if (which == 0) {
          outbd[(size_t)m * DM + nn] = v + bbd[nn];
        } else {
          const int h = nn >> 6, d = nn & 63;
          const int b2 = m >> 11, s = m & 2047;
          const size_t o = (((size_t)(b2 * NH + h)) * SS + s) * HD + d;
          if (which == 1) {
            float sg = 1.f / (1.f + __expf(-radial[h]));
            qb[o] = f2bf((v + bq[nn]) * sg);
          } else if (which == 2) {
            kb[o] = f2bf(v + bk[nn]);
          } else {
            vb[o] = f2bf(v + bv[nn]);
          }
        }
      }
    }
  }
}

// ---------------- K1b: transpose V -> vt[bh][64][2048] ----------------------
__global__ __launch_bounds__(256) void k_vt(
    const unsigned short* __restrict__ vb, unsigned short* __restrict__ vt) {
  __shared__ unsigned short t[64][65];
  const int bh = blockIdx.y, st = blockIdx.x;
  const int tid = threadIdx.x;
  const int r = tid >> 2, c4 = (tid & 3) * 16;
  const unsigned short* src = vb + ((size_t)bh * SS + st * 64 + r) * HD + c4;
  #pragma unroll
  for (int i = 0; i < 16; i += 4) {
    ushort4 v = *(const ushort4*)(src + i);
    t[r][c4 + i + 0] = v.x; t[r][c4 + i + 1] = v.y;
    t[r][c4 + i + 2] = v.z; t[r][c4 + i + 3] = v.w;
  }
  __syncthreads();
  const int dd = tid >> 2, s4 = (tid & 3) * 16;
  unsigned short* dst = vt + ((size_t)bh * HD + dd) * SS + st * 64 + s4;
  #pragma unroll
  for (int i = 0; i < 16; i += 4) {
    ushort4 o;
    o.x = t[s4 + i + 0][dd]; o.y = t[s4 + i + 1][dd];
    o.z = t[s4 + i + 2][dd]; o.w = t[s4 + i + 3][dd];
    *(ushort4*)(dst + i) = o;
  }
}

// ---------------- K2: fused scores + tropical softmax + attn write + PV -----
// r6 structure (best: 277 us total). ONE change: pass-2 computes all 4 subs'
// score/exp into registers first, then issues the 4 nt attn stores
// back-to-back so sub pairs (0,1) and (2,3) complete full 128B lines in the
// write-combine window (was: 64B half-lines separated by ~50 instrs ->
// 1.26x write amplification, ~3.6 TB/s effective).
__global__ __launch_bounds__(256) void k_attn_pv(
    const unsigned short* __restrict__ qb, const unsigned short* __restrict__ kb,
    const unsigned short* __restrict__ vt, const float* __restrict__ tsc,
    float* __restrict__ attn, float* __restrict__ out) {
  __shared__ unsigned short lk[2][64 * 64];                  // 16 KB
  __shared__ unsigned short lv[2][64 * 64];                  // 16 KB
  __shared__ __align__(16) unsigned short pt[4][16 * 64];    // 8 KB
  const int bh = blockIdx.y, qt = blockIdx.x;
  const int tid = threadIdx.x, wave = tid >> 6, lane = tid & 63;
  const int ro = lane & 15, gg = lane >> 4;

  const unsigned short* kb_bh = kb + (size_t)bh * SS * HD;
  const unsigned short* vt_bh = vt + (size_t)bh * HD * SS;

  // staging geometry: thread stages 16B slots (wave*2+i)*64+lane, i=0,1
  int sr0, sc0, sr1, sc1;
  {
    int s0 = (wave * 2 + 0) * 64 + lane;
    int s1 = (wave * 2 + 1) * 64 + lane;
    sr0 = s0 >> 3; sc0 = (s0 & 7) ^ (sr0 & 7);
    sr1 = s1 >> 3; sc1 = (s1 & 7) ^ (sr1 & 7);
  }

#define STAGE_K(buf, kt) do { \
    const unsigned short* g = kb_bh + (size_t)(kt) * 64 * HD; \
    gload_lds16(g + sr0 * 64 + sc0 * 8, (void*)(lk[buf] + (wave * 2 + 0) * 512)); \
    gload_lds16(g + sr1 * 64 + sc1 * 8, (void*)(lk[buf] + (wave * 2 + 1) * 512)); \
  } while (0)
#define STAGE_V(buf, kt) do { \
    const unsigned short* g = vt_bh + (size_t)(kt) * 64; \
    gload_lds16(g + (size_t)sr0 * SS + sc0 * 8, (void*)(lv[buf] + (wave * 2 + 0) * 512)); \
    gload_lds16(g + (size_t)sr1 * SS + sc1 * 8, (void*)(lv[buf] + (wave * 2 + 1) * 512)); \
  } while (0)

  STAGE_K(0, 0);

  // Q straight to registers (one row per lane-group slot, 2x16B)
  const unsigned short* qrow =
      qb + ((size_t)bh * SS + qt * 64 + wave * 16 + ro) * HD;
  short8 aq0 = *(const short8*)(qrow + gg * 8);
  short8 aq1 = *(const short8*)(qrow + 32 + gg * 8);
  const float fac = tsc[0] * 0.125f;  // tropical_scale / sqrt(64)

  __syncthreads();  // drains K(0) stage + Q loads

  // ---- pass 1: row sums of exp(s*fac) ----
  float psum = 0.f;
  int cur = 0;
  for (int ct = 0; ct < 32; ++ct) {
    if (ct < 31) STAGE_K(cur ^ 1, ct + 1);
    const unsigned short* kbuf = lk[cur];
    #pragma unroll
    for (int sub = 0; sub < 4; ++sub) {
      const int rr = sub * 16 + ro;
      const unsigned short* kr = kbuf + rr * 64;
      short8 b0 = *(const short8*)&kr[(gg ^ (rr & 7)) * 8];
      short8 b1 = *(const short8*)&kr[((4 + gg) ^ (rr & 7)) * 8];
      f32x4 sf = {};
      sf = MFMA(b0, aq0, sf);   // lane: q=ro, k = ct*64+sub*16+gg*4+reg
      sf = MFMA(b1, aq1, sf);
      psum += __expf(sf[0] * fac) + __expf(sf[1] * fac)
            + __expf(sf[2] * fac) + __expf(sf[3] * fac);
    }
    __syncthreads();
    cur ^= 1;
  }
  STAGE_K(0, 0);
  STAGE_V(0, 0);
  psum += __shfl_xor(psum, 16);
  psum += __shfl_xor(psum, 32);
  const float rsum = 1.f / (psum + 1e-8f);
  __syncthreads();  // drains stage(0) -> buf0 ready

  // ---- pass 2: recompute, batched nt attn stores, PV ----
  // per chunk: [vmcnt(4) waits this chunk's 4 staged loads][s_barrier]
  //            [issue next chunk's 4 loads][compute 4 subs -> regs]
  //            [4 back-to-back nt stores][cvt+P writes][PV]
  float* ab = attn + ((size_t)bh * SS + qt * 64 + wave * 16 + ro) * SS;
  unsigned short* pw = &pt[wave][0];
  f32x4 acc[4] = {};
  cur = 0;
  for (int ct = 0; ct < 32; ++ct) {
    asm volatile("s_waitcnt vmcnt(4)" ::: "memory");
    __builtin_amdgcn_s_barrier();
    if (ct < 31) { STAGE_K(cur ^ 1, ct + 1); STAGE_V(cur ^ 1, ct + 1); }
    const unsigned short* kbuf = lk[cur];
    const unsigned short* vbuf = lv[cur];
    f32x4 st[4];
    #pragma unroll
    for (int sub = 0; sub < 4; ++sub) {
      const int rr = sub * 16 + ro;
      const unsigned short* kr = kbuf + rr * 64;
      short8 b0 = *(const short8*)&kr[(gg ^ (rr & 7)) * 8];
      short8 b1 = *(const short8*)&kr[((4 + gg) ^ (rr & 7)) * 8];
      f32x4 sf = {};
      sf = MFMA(b0, aq0, sf);
      sf = MFMA(b1, aq1, sf);
      st[sub][0] = __expf(sf[0] * fac) * rsum;
      st[sub][1] = __expf(sf[1] * fac) * rsum;
      st[sub][2] = __expf(sf[2] * fac) * rsum;
      st[sub][3] = __expf(sf[3] * fac) * rsum;
    }
    // 4 stores back-to-back: subs (0,1) complete one 128B line, (2,3) the next
    #pragma unroll
    for (int sub = 0; sub < 4; ++sub)
      __builtin_nontemporal_store(st[sub],
          (f32x4*)(ab + (ct * 4 + sub) * 16 + gg * 4));
    #pragma unroll
    for (int sub = 0; sub < 4; ++sub) {
      unsigned w0, w1;
      asm("v_cvt_pk_bf16_f32 %0, %1, %2" : "=v"(w0) : "v"(st[sub][0]), "v"(st[sub][1]));
      asm("v_cvt_pk_bf16_f32 %0, %1, %2" : "=v"(w1) : "v"(st[sub][2]), "v"(st[sub][3]));
      // P row ro, k-slot = sub*2 + (gg>>1), swizzled by ro&7; 8B half = gg&1
      const int slot = (sub * 2 + (gg >> 1)) ^ (ro & 7);
      *(uint2*)((char*)pw + ro * 128 + slot * 16 + (gg & 1) * 8) = make_uint2(w0, w1);
    }
    // PV: 2 k-steps of 32 over this 64-k chunk
    #pragma unroll
    for (int ks = 0; ks < 2; ++ks) {
      const int pslot = (ks * 4 + gg) ^ (ro & 7);
      short8 pa = *(const short8*)((const char*)pw + ro * 128 + pslot * 16);
      #pragma unroll
      for (int dc = 0; dc < 4; ++dc) {
        const int rr = dc * 16 + ro;
        const int cc = (ks * 4 + gg) ^ (rr & 7);
        short8 bvf = *(const short8*)&vbuf[rr * 64 + cc * 8];
        acc[dc] = MFMA(pa, bvf, acc[dc]);
      }
    }
    cur ^= 1;
  }

  // epilogue: out += PV (boundary already written by k_proj)
  const int b2 = bh >> 4, h = bh & 15;
  const int s0 = qt * 64 + wave * 16 + gg * 4;
  #pragma unroll
  for (int dc = 0; dc < 4; ++dc)
    #pragma unroll
    for (int j = 0; j < 4; ++j) {
      size_t o = ((size_t)b2 * SS + s0 + j) * DM + h * HD + dc * 16 + ro;
      out[o] += acc[dc][j];
    }
#undef STAGE_K
#undef STAGE_V
}

extern "C" void kernel_launch(void* const* d_in, const int* in_sizes, int n_in,
                              void* d_out, int out_size, void* d_ws, size_t ws_size,
                              hipStream_t stream) {
  (void)in_sizes; (void)n_in; (void)out_size; (void)ws_size;
  const float* x   = (const float*)d_in[0];
  const float* Wb  = (const float*)d_in[1];
  const float* bb  = (const float*)d_in[2];
  const float* Wq  = (const float*)d_in[3];
  const float* bq  = (const float*)d_in[4];
  const float* Wk  = (const float*)d_in[5];
  const float* bk  = (const float*)d_in[6];
  const float* Wv  = (const float*)d_in[7];
  const float* bv  = (const float*)d_in[8];
  const float* rad = (const float*)d_in[9];
  const float* tsc = (const float*)d_in[10];

  float* out  = (float*)d_out;
  float* attn = out + (size_t)MTOT * DM;  // second output, also early scratch

  // ws: qb(8MB) kb(8MB) vt(8MB)
  unsigned short* qb = (unsigned short*)d_ws;
  unsigned short* kb = qb + (size_t)4 * 1024 * 1024;
  unsigned short* vt = kb + (size_t)4 * 1024 * 1024;

  // scratch carved from the attn output region (overwritten later by k_attn_pv)
  unsigned short* xb = (unsigned short*)attn;
  unsigned short* wb = xb + (size_t)4 * 1024 * 1024;
  unsigned short* vb = wb + (size_t)4 * 1024 * 1024;

  k_convert<<<2048, 256, 0, stream>>>(x, Wb, Wq, Wk, Wv, xb, wb);
  k_proj<<<dim3(32, 32), 256, 0, stream>>>(xb, wb, bb, bq, bk, bv, rad, out, qb, kb, vb);
  k_vt<<<dim3(32, 32), 256, 0, stream>>>(vb, vt);
  k_attn_pv<<<dim3(32, 32), 256, 0, stream>>>(qb, kb, vt, tsc, attn, out);
}